// Round 7
// baseline (651.650 us; speedup 1.0000x reference)
//
#include <hip/hip_runtime.h>
#include <hip/hip_bf16.h>
#include <stdint.h>

typedef __bf16 bf16;
typedef __attribute__((ext_vector_type(8))) __bf16 bf16x8;
typedef __attribute__((ext_vector_type(4))) float f32x4;

#define L_SEQ 2048
#define C_DIM 2048
#define NBATCH 2
#define M_ROWS (NBATCH * L_SEQ)   // 4096
#define DH 128
#define NHEAD 16
#define WINSZ 256

__device__ __forceinline__ float san(float v, float s) {
    return ((__float_as_uint(v) & 0x7f800000u) == 0x7f800000u) ? s : v;
}

__device__ __forceinline__ bf16x8 pack8(float4 lo, float4 hi) {
    bf16x8 v;
    v[0] = (bf16)lo.x; v[1] = (bf16)lo.y; v[2] = (bf16)lo.z; v[3] = (bf16)lo.w;
    v[4] = (bf16)hi.x; v[5] = (bf16)hi.y; v[6] = (bf16)hi.z; v[7] = (bf16)hi.w;
    return v;
}

// ---------------------------------------------------------------------------
// GEMM (NT): Out[m][n] = sum_k A[m][k]*W[n][k] + bias[n]
// A: fp32 (AF32) or bf16; W/bias fp32 (harness inputs); Out: bf16 or fp32
// (OUTF32). 128x128 tile, BK=32, reg-staged LDS, 4 waves x 4x4
// mfma_f32_16x16x32_bf16. grid.z selects the (W,bias,Out) triple.
// ---------------------------------------------------------------------------
template <bool AF32, bool OUTF32>
__global__ __launch_bounds__(256)
void gemm_bt_bias(const void* __restrict__ Ap,
                  const float* __restrict__ W0, const float* __restrict__ b0, void* O0,
                  const float* __restrict__ W1, const float* __restrict__ b1, void* O1,
                  const float* __restrict__ W2, const float* __restrict__ b2, void* O2,
                  float snt)
{
    const int K = C_DIM, N = C_DIM;
    const float* W = W0; const float* bias = b0; void* Out = O0;
    if (blockIdx.z == 1)      { W = W1; bias = b1; Out = O1; }
    else if (blockIdx.z == 2) { W = W2; bias = b2; Out = O2; }

    __shared__ bf16 As[128 * 32];
    __shared__ bf16 Bs[128 * 32];

    const int tid  = threadIdx.x;
    const int lane = tid & 63;
    const int m0 = blockIdx.x * 128;
    const int n0 = blockIdx.y * 128;

    const int wave = tid >> 6;
    const int wm = (wave >> 1) * 64;
    const int wn = (wave & 1) * 64;

    const int srow = tid >> 2;         // 0..63
    const int scol = (tid & 3) * 8;    // 0/8/16/24

    f32x4 acc[4][4] = {};

    const int fr = lane & 15;
    const int fq = (lane >> 4) * 8;

    for (int k0 = 0; k0 < K; k0 += 32) {
        bf16x8 ra[2], rb[2];
        #pragma unroll
        for (int p = 0; p < 2; p++) {
            const size_t aoff = (size_t)(m0 + p * 64 + srow) * K + k0 + scol;
            if (AF32) {
                const float* A = (const float*)Ap;
                float4 lo = *(const float4*)(A + aoff);
                float4 hi = *(const float4*)(A + aoff + 4);
                ra[p] = pack8(lo, hi);
            } else {
                const bf16* A = (const bf16*)Ap;
                ra[p] = *(const bf16x8*)(A + aoff);
            }
            const size_t boff = (size_t)(n0 + p * 64 + srow) * K + k0 + scol;
            float4 wlo = *(const float4*)(W + boff);
            float4 whi = *(const float4*)(W + boff + 4);
            rb[p] = pack8(wlo, whi);
        }
        __syncthreads();
        #pragma unroll
        for (int p = 0; p < 2; p++) {
            *(bf16x8*)&As[(p * 64 + srow) * 32 + scol] = ra[p];
            *(bf16x8*)&Bs[(p * 64 + srow) * 32 + scol] = rb[p];
        }
        __syncthreads();

        bf16x8 af[4], bfr[4];
        #pragma unroll
        for (int s = 0; s < 4; s++)
            af[s] = *(const bf16x8*)&As[(wm + s * 16 + fr) * 32 + fq];
        #pragma unroll
        for (int s = 0; s < 4; s++)
            bfr[s] = *(const bf16x8*)&Bs[(wn + s * 16 + fr) * 32 + fq];
        #pragma unroll
        for (int sm = 0; sm < 4; sm++)
            #pragma unroll
            for (int sn = 0; sn < 4; sn++)
                acc[sm][sn] = __builtin_amdgcn_mfma_f32_16x16x32_bf16(af[sm], bfr[sn], acc[sm][sn], 0, 0, 0);
    }

    // epilogue: C/D layout col=lane&15, row=(lane>>4)*4+reg (m89-verified)
    const int r0 = (lane >> 4) * 4;
    const int cn = lane & 15;
    #pragma unroll
    for (int sn = 0; sn < 4; sn++) {
        const int n = n0 + wn + sn * 16 + cn;
        const float bv = bias[n];
        #pragma unroll
        for (int sm = 0; sm < 4; sm++) {
            const int m = m0 + wm + sm * 16 + r0;
            #pragma unroll
            for (int r = 0; r < 4; r++) {
                const float v = san(acc[sm][sn][r] + bv, snt);
                if (OUTF32) ((float*)Out)[(size_t)(m + r) * N + n] = v;
                else        ((bf16*)Out)[(size_t)(m + r) * N + n] = (bf16)v;
            }
        }
    }
}

// ---------------------------------------------------------------------------
// Sliding-window causal attention (VALU flash), WIN=256, D=128, bf16 in/out.
// Verified vs serial reference in round 6 (all check bits clean).
// Q and Oattn alias (in-place over d_out's first half viewed as bf16).
// ---------------------------------------------------------------------------
#define QPAD 136

__device__ __forceinline__ void unpack8(uint4 v, float* f) {
    const uint32_t w0 = v.x, w1 = v.y, w2 = v.z, w3 = v.w;
    f[0] = __uint_as_float(w0 << 16); f[1] = __uint_as_float(w0 & 0xffff0000u);
    f[2] = __uint_as_float(w1 << 16); f[3] = __uint_as_float(w1 & 0xffff0000u);
    f[4] = __uint_as_float(w2 << 16); f[5] = __uint_as_float(w2 & 0xffff0000u);
    f[6] = __uint_as_float(w3 << 16); f[7] = __uint_as_float(w3 & 0xffff0000u);
}

__global__ __launch_bounds__(256)
void swa_attn(const bf16* Q, const bf16* __restrict__ Kp,
              const bf16* __restrict__ V, bf16* Oattn, float snt)
{
    __shared__ bf16 Qs[64 * QPAD];
    __shared__ bf16 Ks[64 * QPAD];
    __shared__ bf16 Vs[64 * 128];
    __shared__ bf16 Ps[64 * 64];

    const int tid = threadIdx.x;
    const int q0  = blockIdx.x * 64;
    const int h   = blockIdx.y;
    const int b   = blockIdx.z;
    const size_t base = (size_t)b * L_SEQ * C_DIM + (size_t)h * DH;

    {
        const int rr = tid >> 4;
        const int cc = (tid & 15) * 8;
        #pragma unroll
        for (int p = 0; p < 4; p++) {
            const int r = p * 16 + rr;
            *(uint4*)&Qs[r * QPAD + cc] = *(const uint4*)(Q + base + (size_t)(q0 + r) * C_DIM + cc);
        }
    }

    const int ql  = tid >> 2;
    const int sub = tid & 3;
    const int ig  = q0 + ql;
    const float scale = 0.08838834764831845f;

    float m_run = -1e30f, l_run = 0.0f;
    float Oa[32];
    #pragma unroll
    for (int j = 0; j < 32; j++) Oa[j] = 0.0f;

    for (int kb = 0; kb < 5; kb++) {
        const int s = q0 - 256 + kb * 64;
        if (s < 0) continue;
        __syncthreads();
        {
            const int rr = tid >> 4;
            const int cc = (tid & 15) * 8;
            #pragma unroll
            for (int p = 0; p < 4; p++) {
                const int r = p * 16 + rr;
                *(uint4*)&Ks[r * QPAD + cc] = *(const uint4*)(Kp + base + (size_t)(s + r) * C_DIM + cc);
                *(uint4*)&Vs[r * 128 + cc]  = *(const uint4*)(V  + base + (size_t)(s + r) * C_DIM + cc);
            }
        }
        __syncthreads();

        float sc[16];
        #pragma unroll
        for (int ks = 0; ks < 16; ks++) sc[ks] = 0.0f;

        for (int d8 = 0; d8 < 16; d8++) {
            float qf[8];
            unpack8(*(const uint4*)&Qs[ql * QPAD + d8 * 8], qf);
            #pragma unroll
            for (int ks = 0; ks < 16; ks++) {
                float kf[8];
                unpack8(*(const uint4*)&Ks[(ks * 4 + sub) * QPAD + d8 * 8], kf);
                #pragma unroll
                for (int j = 0; j < 8; j++) sc[ks] = fmaf(qf[j], kf[j], sc[ks]);
            }
        }

        float bm = -1e30f;
        unsigned amask = 0;
        #pragma unroll
        for (int ks = 0; ks < 16; ks++) {
            const int j = s + ks * 4 + sub;
            const bool allow = (j <= ig) && (j > ig - WINSZ);
            sc[ks] = allow ? sc[ks] * scale : -1e30f;
            if (allow) amask |= (1u << ks);
            bm = fmaxf(bm, sc[ks]);
        }
        bm = fmaxf(bm, __shfl_xor(bm, 1, 64));
        bm = fmaxf(bm, __shfl_xor(bm, 2, 64));
        const float m_new = fmaxf(m_run, bm);
        const float alpha = __expf(m_run - m_new);
        float ps = 0.0f;
        float pv[16];
        #pragma unroll
        for (int ks = 0; ks < 16; ks++) {
            const float e = __expf(sc[ks] - m_new);
            pv[ks] = ((amask >> ks) & 1u) ? e : 0.0f;
            ps += pv[ks];
        }
        ps += __shfl_xor(ps, 1, 64);
        ps += __shfl_xor(ps, 2, 64);
        l_run = l_run * alpha + ps;
        m_run = m_new;

        #pragma unroll
        for (int ks = 0; ks < 16; ks++)
            Ps[(ks * 4 + sub) * 64 + ql] = (bf16)pv[ks];
        #pragma unroll
        for (int j = 0; j < 32; j++) Oa[j] *= alpha;
        __syncthreads();

        const int d0 = sub * 32;
        for (int k = 0; k < 64; k++) {
            const float p = (float)Ps[k * 64 + ql];
            float vf[8];
            #pragma unroll
            for (int c = 0; c < 4; c++) {
                unpack8(*(const uint4*)&Vs[k * 128 + d0 + c * 8], vf);
                #pragma unroll
                for (int j = 0; j < 8; j++)
                    Oa[c * 8 + j] = fmaf(p, vf[j], Oa[c * 8 + j]);
            }
        }
    }

    const float inv_l = 1.0f / l_run;
    const int d0 = sub * 32;
    bf16* op = Oattn + base + (size_t)ig * C_DIM + d0;
    #pragma unroll
    for (int c = 0; c < 4; c++) {
        bf16x8 ov;
        #pragma unroll
        for (int j = 0; j < 8; j++) ov[j] = (bf16)san(Oa[c * 8 + j] * inv_l, snt);
        *(bf16x8*)(op + c * 8) = ov;
    }
}

// layout-surprise signal (fp32 output now)
__global__ void fill_signal(float* out, int n, float v) {
    for (int i = blockIdx.x * blockDim.x + threadIdx.x; i < n; i += gridDim.x * blockDim.x)
        out[i] = v;
}

// ---------------------------------------------------------------------------
extern "C" void kernel_launch(void* const* d_in, const int* in_sizes, int n_in,
                              void* d_out, int out_size, void* d_ws, size_t ws_size,
                              hipStream_t stream) {
    const size_t sz      = (size_t)M_ROWS * C_DIM;   // 8388608 elements
    const size_t bfbytes = sz * sizeof(bf16);        // 16.78 MB per bf16 buffer

    // host-side layout validation (signals through absmax)
    const int expn[9] = {8388608, 4194304, 2048, 4194304, 2048,
                         4194304, 2048, 4194304, 2048};
    float sig = 0.0f;
    if (n_in != 9) sig = 1100.0f;
    else {
        for (int i = 0; i < 9; i++)
            if (in_sizes[i] != expn[i]) { sig = 1200.0f + 100.0f * i; break; }
    }
    if (sig == 0.0f && out_size != (int)sz) sig = 2100.0f;
    if (sig == 0.0f && ws_size < 2 * bfbytes) sig = 3000.0f + 10.0f * (float)(ws_size >> 20);
    if (sig != 0.0f) {
        fill_signal<<<512, 256, 0, stream>>>((float*)d_out, (int)sz, sig);
        return;
    }

    const float* x  = (const float*)d_in[0];
    const float* Wq = (const float*)d_in[1];
    const float* bq = (const float*)d_in[2];
    const float* Wk = (const float*)d_in[3];
    const float* bk = (const float*)d_in[4];
    const float* Wv = (const float*)d_in[5];
    const float* bv = (const float*)d_in[6];
    const float* Wo = (const float*)d_in[7];
    const float* bo = (const float*)d_in[8];

    bf16*  kws   = (bf16*)d_ws;        // K (bf16), later reused for O_att
    bf16*  vws   = kws + sz;           // V (bf16)
    bf16*  qscr  = (bf16*)d_out;       // Q / O_att (bf16) in d_out's first half
    float* out32 = (float*)d_out;      // final fp32 output

    // 1) QKV projections (fp32 in, bf16 out): Q->d_out-scratch, K,V->ws
    gemm_bt_bias<true, false><<<dim3(32, 16, 3), 256, 0, stream>>>(
        (const void*)x, Wq, bq, (void*)qscr, Wk, bk, (void*)kws,
        Wv, bv, (void*)vws, 111.0f);

    // 2) attention, O_att written in place over Q (bf16)
    swa_attn<<<dim3(L_SEQ / 64, NHEAD, NBATCH), 256, 0, stream>>>(
        qscr, kws, vws, qscr, 222.0f);

    // 3) move O_att (bf16) into the dead K region before fp32 overwrite
    hipMemcpyAsync(kws, qscr, bfbytes, hipMemcpyDeviceToDevice, stream);

    // 4) output projection (bf16 in, fp32 out): full d_out overwrite
    gemm_bt_bias<false, true><<<dim3(32, 16, 1), 256, 0, stream>>>(
        (const void*)kws, Wo, bo, (void*)out32, Wo, bo, (void*)out32,
        Wo, bo, (void*)out32, 444.0f);
}